// Round 10
// baseline (50.470 us; speedup 1.0000x reference)
//
#include <hip/hip_runtime.h>
#include <stdint.h>

// loss = sum_{b,m,n} | dot(src[b,n,:], tgts[b,m,n,:]) |
// B=64, M=16, N=64, D=1024
//
// R10 = R9 (best: 49.60 us) with two changes:
//  1. src row loaded straight to VGPRs (plain global_load_dwordx4, no LDS
//     staging) -> srcb's 16 KiB reclaimed for a FOUR-deep ring
//     (ring[4][4][1024] = 64 KiB, still 2 blocks/CU). Steady state now
//     holds 3 rows = 12 KiB/wave in flight, s_waitcnt vmcnt(12).
//  2. per-row shuffle reduces DEFERRED: each step stores its lane-partial
//     dot in p[mi]; one batched tail of 16 independent butterflies
//     (pipelines ~6x better than 16 serial chains on the critical path).
// Finalization: separate 1-block reduce dispatch (proven best, R8).

typedef __attribute__((ext_vector_type(4))) float f32x4;
typedef const __attribute__((address_space(1))) void* gvp;
typedef __attribute__((address_space(3))) void* svp;

#define GLDS(gp, lp) \
  __builtin_amdgcn_global_load_lds((gvp)(gp), (svp)(lp), 16, 0, 0)

#define WAITV(n)   asm volatile("s_waitcnt vmcnt(" #n ")" ::: "memory")
#define WAITLGKM() asm volatile("s_waitcnt lgkmcnt(0)" ::: "memory")
#define CFENCE()   asm volatile("" ::: "memory")

__global__ __launch_bounds__(256) void orth_loss_main(
    const float* __restrict__ src,
    const float* __restrict__ tgts,
    float* __restrict__ partials)
{
    __shared__ float ring[4][4][1024];   // 4 waves x 4 row-buffers x 4 KiB
    __shared__ float sbuf[4];

    const int wave = threadIdx.x >> 6;   // 0..3
    const int lane = threadIdx.x & 63;

    const int w = blockIdx.x * 4 + wave;    // 0..4095, exact grid
    const int n = w & 63;                   // N = 64
    const int b = w >> 6;                   // B = 64

    // ---- src row -> VGPRs (issued first; drains during prologue) ----
    const f32x4* __restrict__ sp =
        reinterpret_cast<const f32x4*>(src + ((size_t)(b * 64 + n)) * 1024);
    const f32x4 s0 = sp[lane];
    const f32x4 s1 = sp[lane + 64];
    const f32x4 s2 = sp[lane + 128];
    const f32x4 s3 = sp[lane + 192];

    const int    base_row = (b * 16) * 64 + n;      // m = 0..15
    const float* trow = tgts + (size_t)base_row * 1024 + lane * 4;
    const size_t mstride = (size_t)64 * 1024;       // floats between m-rows

    CFENCE();
    // ---- prologue: rows 0..3 -> ring slots 0..3 (16 GLDS ops) ----
#pragma unroll
    for (int r = 0; r < 4; ++r) {
#pragma unroll
        for (int k = 0; k < 4; ++k)
            GLDS(trow + r * mstride + k * 256, &ring[wave][r][k * 256]);
    }

    float p[16];   // per-lane partial dots, statically indexed only

    // step MI: wait vmcnt(WN) (row MI complete, 3 rows in flight),
    // ds_read slot MI%4, 16 FMAs into p[MI], reissue row MI+4 into the
    // just-read slot. Tail waits: 12, 12, 12, 12 -> 12, 8, 4, 0.
#define STEP(MI, DO_ISSUE, WN) do {                                          \
      WAITV(WN);                                                             \
      const f32x4* lb_ = (const f32x4*)&ring[wave][(MI) % 4][0];             \
      const f32x4 t0 = lb_[lane];                                            \
      const f32x4 t1 = lb_[lane + 64];                                       \
      const f32x4 t2 = lb_[lane + 128];                                      \
      const f32x4 t3 = lb_[lane + 192];                                      \
      float dot = 0.0f;                                                      \
      dot = fmaf(t0.x, s0.x, dot); dot = fmaf(t0.y, s0.y, dot);              \
      dot = fmaf(t0.z, s0.z, dot); dot = fmaf(t0.w, s0.w, dot);              \
      dot = fmaf(t1.x, s1.x, dot); dot = fmaf(t1.y, s1.y, dot);              \
      dot = fmaf(t1.z, s1.z, dot); dot = fmaf(t1.w, s1.w, dot);              \
      dot = fmaf(t2.x, s2.x, dot); dot = fmaf(t2.y, s2.y, dot);              \
      dot = fmaf(t2.z, s2.z, dot); dot = fmaf(t2.w, s2.w, dot);              \
      dot = fmaf(t3.x, s3.x, dot); dot = fmaf(t3.y, s3.y, dot);              \
      dot = fmaf(t3.z, s3.z, dot); dot = fmaf(t3.w, s3.w, dot);              \
      p[MI] = dot;                                                           \
      CFENCE();                                                              \
      if (DO_ISSUE) {                                                        \
        WAITLGKM(); /* slot's ds_reads complete before overwrite */          \
        CFENCE();                                                            \
        _Pragma("unroll")                                                    \
        for (int k = 0; k < 4; ++k)                                          \
            GLDS(trow + ((MI) + 4) * mstride + k * 256,                      \
                 &ring[wave][(MI) % 4][k * 256]);                            \
        CFENCE();                                                            \
      }                                                                      \
    } while (0)

    STEP( 0, 1, 12);
    STEP( 1, 1, 12);
    STEP( 2, 1, 12);
    STEP( 3, 1, 12);
    STEP( 4, 1, 12);
    STEP( 5, 1, 12);
    STEP( 6, 1, 12);
    STEP( 7, 1, 12);
    STEP( 8, 1, 12);
    STEP( 9, 1, 12);
    STEP(10, 1, 12);
    STEP(11, 1, 12);
    STEP(12, 0, 12);
    STEP(13, 0, 8);
    STEP(14, 0, 4);
    STEP(15, 0, 0);
#undef STEP

    // ---- batched tail: 16 independent 64-lane butterflies ----
    float local = 0.0f;
#pragma unroll
    for (int mi = 0; mi < 16; ++mi) {
        float d = p[mi];
#pragma unroll
        for (int off = 32; off > 0; off >>= 1)
            d += __shfl_down(d, off, 64);
        if (lane == 0) local += fabsf(d);
    }

    if (lane == 0) sbuf[wave] = local;
    __syncthreads();
    if (threadIdx.x == 0)
        partials[blockIdx.x] = sbuf[0] + sbuf[1] + sbuf[2] + sbuf[3];
}

__global__ __launch_bounds__(256) void reduce_partials(
    const float* __restrict__ partials, float* __restrict__ out, int n)
{
    __shared__ float sb[4];
    const int lane = threadIdx.x & 63;
    const int wv   = threadIdx.x >> 6;
    float s = 0.0f;
    for (int i = threadIdx.x; i < n; i += 256) s += partials[i];
#pragma unroll
    for (int off = 32; off > 0; off >>= 1) s += __shfl_down(s, off, 64);
    if (lane == 0) sb[wv] = s;
    __syncthreads();
    if (threadIdx.x == 0) out[0] = sb[0] + sb[1] + sb[2] + sb[3];
}

extern "C" void kernel_launch(void* const* d_in, const int* in_sizes, int n_in,
                              void* d_out, int out_size, void* d_ws, size_t ws_size,
                              hipStream_t stream) {
    const float* src  = (const float*)d_in[0];   // [B, N, D]
    const float* tgts = (const float*)d_in[1];   // [B, M, N, D]
    float* out      = (float*)d_out;             // [1]
    float* partials = (float*)d_ws;              // 1024 floats

    // one wave per (b, n): B*N waves = 4096, 4 waves/block
    const int total_waves = in_sizes[0] / 1024;  // 4096
    const int blocks = total_waves / 4;          // 1024

    orth_loss_main<<<blocks, 256, 0, stream>>>(src, tgts, partials);
    reduce_partials<<<1, 256, 0, stream>>>(partials, out, blocks);
}

// Round 11
// 49.778 us; speedup vs baseline: 1.0139x; 1.0139x over previous
//
#include <hip/hip_runtime.h>
#include <stdint.h>

// loss = sum_{b,m,n} | dot(src[b,n,:], tgts[b,m,n,:]) |
// B=64, M=16, N=64, D=1024
//
// FINAL = R9 (best measured: 49.60 us, ~5.75 TB/s logical).
// DMA-streaming (T3/T4): one wave per (b, n) covering all 16 m-rows; all
// fetches via global_load_lds into a per-wave 3-deep LDS ring; hand-counted
// s_waitcnt vmcnt(8) never drains to 0 in steady state (2 rows = 8 KiB
// always in flight per wave). src row staged once via LDS then kept in
// registers. Next-row GLDS issued before the serial shuffle-reduce.
// Finalization: separate 1-block reduce dispatch (measured best vs fused
// ticket protocol [-4.4x] and memset+atomicAdd [-6 us]).

typedef __attribute__((ext_vector_type(4))) float f32x4;
typedef const __attribute__((address_space(1))) void* gvp;
typedef __attribute__((address_space(3))) void* svp;

#define GLDS(gp, lp) \
  __builtin_amdgcn_global_load_lds((gvp)(gp), (svp)(lp), 16, 0, 0)

#define WAITV(n)  asm volatile("s_waitcnt vmcnt(" #n ")" ::: "memory")
#define WAITLGKM() asm volatile("s_waitcnt lgkmcnt(0)" ::: "memory")
#define CFENCE() asm volatile("" ::: "memory")

__global__ __launch_bounds__(256) void orth_loss_main(
    const float* __restrict__ src,
    const float* __restrict__ tgts,
    float* __restrict__ partials)
{
    __shared__ float ring[4][3][1024];   // 4 waves x 3 row-buffers x 4 KiB
    __shared__ float srcb[4][1024];      // 4 waves x src row
    __shared__ float sbuf[4];

    const int wave = threadIdx.x >> 6;   // 0..3
    const int lane = threadIdx.x & 63;

    const int w = blockIdx.x * 4 + wave;    // 0..4095, exact grid
    const int n = w & 63;                   // N = 64
    const int b = w >> 6;                   // B = 64

    const float* srow = src + ((size_t)(b * 64 + n)) * 1024 + lane * 4;
    const int    base_row = (b * 16) * 64 + n;      // m = 0..15
    const float* trow = tgts + (size_t)base_row * 1024 + lane * 4;
    const size_t mstride = (size_t)64 * 1024;       // floats between m-rows

    // ---- prologue: src (4 ops) + rows 0,1,2 (12 ops) = 16 outstanding ----
#pragma unroll
    for (int k = 0; k < 4; ++k)
        GLDS(srow + k * 256, &srcb[wave][k * 256]);
#pragma unroll
    for (int r = 0; r < 3; ++r) {
#pragma unroll
        for (int k = 0; k < 4; ++k)
            GLDS(trow + r * mstride + k * 256, &ring[wave][r][k * 256]);
    }

    float local = 0.0f;
    f32x4 s0, s1, s2, s3;

    // step MI: wait vmcnt(WN) (row MI + [src at MI=0] done, 2 rows in
    // flight), ds_read row, FMA, issue row MI+3 into the just-read slot,
    // then the serial shuffle reduce. Tail waits: 8 ... 8, 4, 0.
#define STEP(MI, DO_ISSUE, WN) do {                                          \
      WAITV(WN);                                                             \
      if ((MI) == 0) {                                                       \
        const f32x4* sb_ = (const f32x4*)&srcb[wave][0];                     \
        s0 = sb_[lane];       s1 = sb_[lane + 64];                           \
        s2 = sb_[lane + 128]; s3 = sb_[lane + 192];                          \
      }                                                                      \
      const f32x4* lb_ = (const f32x4*)&ring[wave][(MI) % 3][0];             \
      const f32x4 t0 = lb_[lane];                                            \
      const f32x4 t1 = lb_[lane + 64];                                       \
      const f32x4 t2 = lb_[lane + 128];                                      \
      const f32x4 t3 = lb_[lane + 192];                                      \
      float dot = 0.0f;                                                      \
      dot = fmaf(t0.x, s0.x, dot); dot = fmaf(t0.y, s0.y, dot);              \
      dot = fmaf(t0.z, s0.z, dot); dot = fmaf(t0.w, s0.w, dot);              \
      dot = fmaf(t1.x, s1.x, dot); dot = fmaf(t1.y, s1.y, dot);              \
      dot = fmaf(t1.z, s1.z, dot); dot = fmaf(t1.w, s1.w, dot);              \
      dot = fmaf(t2.x, s2.x, dot); dot = fmaf(t2.y, s2.y, dot);              \
      dot = fmaf(t2.z, s2.z, dot); dot = fmaf(t2.w, s2.w, dot);              \
      dot = fmaf(t3.x, s3.x, dot); dot = fmaf(t3.y, s3.y, dot);              \
      dot = fmaf(t3.z, s3.z, dot); dot = fmaf(t3.w, s3.w, dot);              \
      CFENCE();                                                              \
      if (DO_ISSUE) {                                                        \
        WAITLGKM(); /* ring-slot ds_reads complete before overwrite */       \
        CFENCE();                                                            \
        _Pragma("unroll")                                                    \
        for (int k = 0; k < 4; ++k)                                          \
            GLDS(trow + ((MI) + 3) * mstride + k * 256,                      \
                 &ring[wave][(MI) % 3][k * 256]);                            \
        CFENCE();                                                            \
      }                                                                      \
      _Pragma("unroll")                                                      \
      for (int off = 32; off > 0; off >>= 1)                                 \
          dot += __shfl_down(dot, off, 64);                                  \
      if (lane == 0) local += fabsf(dot);                                    \
    } while (0)

    STEP( 0, 1, 8);
    STEP( 1, 1, 8);
    STEP( 2, 1, 8);
    STEP( 3, 1, 8);
    STEP( 4, 1, 8);
    STEP( 5, 1, 8);
    STEP( 6, 1, 8);
    STEP( 7, 1, 8);
    STEP( 8, 1, 8);
    STEP( 9, 1, 8);
    STEP(10, 1, 8);
    STEP(11, 1, 8);
    STEP(12, 1, 8);
    STEP(13, 0, 8);
    STEP(14, 0, 4);
    STEP(15, 0, 0);
#undef STEP

    if (lane == 0) sbuf[wave] = local;
    __syncthreads();
    if (threadIdx.x == 0)
        partials[blockIdx.x] = sbuf[0] + sbuf[1] + sbuf[2] + sbuf[3];
}

__global__ __launch_bounds__(256) void reduce_partials(
    const float* __restrict__ partials, float* __restrict__ out, int n)
{
    __shared__ float sb[4];
    const int lane = threadIdx.x & 63;
    const int wv   = threadIdx.x >> 6;
    float s = 0.0f;
    for (int i = threadIdx.x; i < n; i += 256) s += partials[i];
#pragma unroll
    for (int off = 32; off > 0; off >>= 1) s += __shfl_down(s, off, 64);
    if (lane == 0) sb[wv] = s;
    __syncthreads();
    if (threadIdx.x == 0) out[0] = sb[0] + sb[1] + sb[2] + sb[3];
}

extern "C" void kernel_launch(void* const* d_in, const int* in_sizes, int n_in,
                              void* d_out, int out_size, void* d_ws, size_t ws_size,
                              hipStream_t stream) {
    const float* src  = (const float*)d_in[0];   // [B, N, D]
    const float* tgts = (const float*)d_in[1];   // [B, M, N, D]
    float* out      = (float*)d_out;             // [1]
    float* partials = (float*)d_ws;              // 1024 floats

    // one wave per (b, n): B*N waves = 4096, 4 waves/block
    const int total_waves = in_sizes[0] / 1024;  // 4096
    const int blocks = total_waves / 4;          // 1024

    orth_loss_main<<<blocks, 256, 0, stream>>>(src, tgts, partials);
    reduce_partials<<<1, 256, 0, stream>>>(partials, out, blocks);
}